// Round 1
// baseline (724.281 us; speedup 1.0000x reference)
//
#include <hip/hip_runtime.h>
#include <hip/hip_bf16.h>

#define B_ 32
#define D_ 256
#define N_ 16384
#define F_ 256
#define K_ 32

#define NSPLIT 32
#define NSLICE (N_ / NSPLIT)   // 512
#define NT 16
#define FPAD 260               // 16B-aligned row stride for v tile (n-major)
#define OPAD 36                // 16B-aligned row stride for omega tile (n-major)

__device__ __forceinline__ float bf2f(unsigned short u) {
    unsigned int x = ((unsigned int)u) << 16;
    return __uint_as_float(x);
}

// ---------------- Kernel A: sims[b][n] = -(sum_d q[b][d]*keys[b][d][n]) / 16 ----------------
__global__ __launch_bounds__(256) void sims_kernel(
    const float* __restrict__ q, const float* __restrict__ keys, float* __restrict__ sims)
{
    const int nt = N_ / 1024;                 // 16 n-tiles per batch
    int b = blockIdx.x / nt;
    int tile = blockIdx.x % nt;
    int n0 = tile * 1024 + threadIdx.x * 4;

    __shared__ float qs[D_];
    qs[threadIdx.x] = q[b * D_ + threadIdx.x];   // blockDim == D_ == 256
    __syncthreads();

    const float* kb = keys + (size_t)b * D_ * N_ + n0;
    float ax = 0.f, ay = 0.f, az = 0.f, aw = 0.f;
    #pragma unroll 4
    for (int d = 0; d < D_; ++d) {
        float4 kv = *reinterpret_cast<const float4*>(kb + (size_t)d * N_);
        float qd = qs[d];
        ax = fmaf(qd, kv.x, ax); ay = fmaf(qd, kv.y, ay);
        az = fmaf(qd, kv.z, az); aw = fmaf(qd, kv.w, aw);
    }
    const float sc = -0.0625f;   // -1/sqrt(256)
    float4 o = make_float4(ax * sc, ay * sc, az * sc, aw * sc);
    *reinterpret_cast<float4*>(sims + b * N_ + n0) = o;
}

// ---------------- Kernel B: omega iterations (one 1024-thread block per batch) ----------------
__device__ __forceinline__ float blk_max(float v, volatile float* red) {
    #pragma unroll
    for (int off = 32; off > 0; off >>= 1) v = fmaxf(v, __shfl_xor(v, off));
    if ((threadIdx.x & 63) == 0) red[threadIdx.x >> 6] = v;
    __syncthreads();
    if (threadIdx.x < 64) {
        float w = (threadIdx.x < 16) ? red[threadIdx.x] : -3.0e38f;
        #pragma unroll
        for (int off = 8; off > 0; off >>= 1) w = fmaxf(w, __shfl_xor(w, off));
        if (threadIdx.x == 0) red[16] = w;
    }
    __syncthreads();
    return red[16];
}
__device__ __forceinline__ float blk_sum(float v, volatile float* red) {
    #pragma unroll
    for (int off = 32; off > 0; off >>= 1) v += __shfl_xor(v, off);
    if ((threadIdx.x & 63) == 0) red[threadIdx.x >> 6] = v;
    __syncthreads();
    if (threadIdx.x < 64) {
        float w = (threadIdx.x < 16) ? red[threadIdx.x] : 0.0f;
        #pragma unroll
        for (int off = 8; off > 0; off >>= 1) w += __shfl_xor(w, off);
        if (threadIdx.x == 0) red[16] = w;
    }
    __syncthreads();
    return red[16];
}

__global__ __launch_bounds__(1024) void omega_kernel(
    const float* __restrict__ sims, __hip_bfloat16* __restrict__ omega)
{
    int b = blockIdx.x, t = threadIdx.x;
    __shared__ float red1[17];   // for max reductions
    __shared__ float red2[17];   // for sum reductions (separate -> no entry sync needed)

    float a[16];
    float m0 = -3.0e38f;
    #pragma unroll
    for (int j = 0; j < 16; ++j) {
        a[j] = sims[b * N_ + t + 1024 * j];
        m0 = fmaxf(m0, a[j]);
    }
    m0 = blk_max(m0, red1);
    float zs = 0.f;
    #pragma unroll
    for (int j = 0; j < 16; ++j) { a[j] = expf(a[j] - m0); zs += a[j]; }
    float Z = blk_sum(zs, red2);
    float inv = 1.0f / Z;
    #pragma unroll
    for (int j = 0; j < 16; ++j) a[j] *= inv;

    for (int k = 0; k < K_; ++k) {
        float m = -3.0e38f;
        #pragma unroll
        for (int j = 0; j < 16; ++j) m = fmaxf(m, a[j]);
        m = blk_max(2.0f * m, red1);          // max over n of 2*alpha (x2 exact)
        float e[16]; float zz = 0.f;
        #pragma unroll
        for (int j = 0; j < 16; ++j) { e[j] = expf(2.0f * a[j] - m); zz += e[j]; }
        float Zk = blk_sum(zz, red2);
        float izk = 1.0f / Zk;
        __hip_bfloat16* ob = omega + ((size_t)b * K_ + k) * N_;
        #pragma unroll
        for (int j = 0; j < 16; ++j) {
            float om = e[j] * izk;
            ob[t + 1024 * j] = __float2bfloat16(om);
            a[j] += log1pf(-om);              // alpha update uses full f32 om
        }
    }
}

// ---------------- Kernel C: partial PV: part[b][ns][k][f] = sum_{n in slice} om[k][n]*v[f][n] --
__global__ __launch_bounds__(128) void pv_kernel(
    const float* __restrict__ values, const __hip_bfloat16* __restrict__ omega,
    float* __restrict__ part)
{
    int ns = blockIdx.x % NSPLIT;
    int b  = blockIdx.x / NSPLIT;
    int t = threadIdx.x;
    int kg = t >> 5;            // 0..3
    int fg = t & 31;            // 0..31
    int k0 = kg * 8;
    int f0 = fg * 4;

    __shared__ float vs[NT][FPAD];   // n-major v tile
    __shared__ float os[NT][OPAD];   // n-major omega tile

    float acc[8][8];
    #pragma unroll
    for (int i = 0; i < 8; ++i)
        #pragma unroll
        for (int j = 0; j < 8; ++j) acc[i][j] = 0.f;

    const float* vb = values + (size_t)b * F_ * N_;
    const unsigned short* ob = reinterpret_cast<const unsigned short*>(omega) + (size_t)b * K_ * N_;
    int nbase0 = ns * NSLICE;

    int sr = t >> 2;            // 0..31 (row base: f for v, k for omega)
    int sc = (t & 3) * 4;       // 0,4,8,12 (n offset)

    for (int nb = 0; nb < NSLICE; nb += NT) {
        int nbase = nbase0 + nb;
        __syncthreads();   // previous-iter LDS reads done
        // stage v: 256 f x 16 n, transposed into LDS
        #pragma unroll
        for (int p = 0; p < 8; ++p) {
            int f = sr + 32 * p;
            float4 vv = *reinterpret_cast<const float4*>(vb + (size_t)f * N_ + nbase + sc);
            vs[sc + 0][f] = vv.x;
            vs[sc + 1][f] = vv.y;
            vs[sc + 2][f] = vv.z;
            vs[sc + 3][f] = vv.w;
        }
        // stage omega: 32 k x 16 n (bf16 -> f32), transposed
        {
            ushort4 ov = *reinterpret_cast<const ushort4*>(ob + (size_t)sr * N_ + nbase + sc);
            os[sc + 0][sr] = bf2f(ov.x);
            os[sc + 1][sr] = bf2f(ov.y);
            os[sc + 2][sr] = bf2f(ov.z);
            os[sc + 3][sr] = bf2f(ov.w);
        }
        __syncthreads();
        // compute: per n, 4x b128 reads (contiguous-512B across wave) + 64 FMA
        #pragma unroll
        for (int n = 0; n < NT; ++n) {
            float4 o0  = *reinterpret_cast<const float4*>(&os[n][k0]);
            float4 o1  = *reinterpret_cast<const float4*>(&os[n][k0 + 4]);
            float4 va  = *reinterpret_cast<const float4*>(&vs[n][f0]);
            float4 vb4 = *reinterpret_cast<const float4*>(&vs[n][f0 + 128]);
            float om[8] = {o0.x, o0.y, o0.z, o0.w, o1.x, o1.y, o1.z, o1.w};
            float vv[8] = {va.x, va.y, va.z, va.w, vb4.x, vb4.y, vb4.z, vb4.w};
            #pragma unroll
            for (int i = 0; i < 8; ++i)
                #pragma unroll
                for (int j = 0; j < 8; ++j)
                    acc[i][j] = fmaf(om[i], vv[j], acc[i][j]);
        }
    }

    // write partials: part[b][ns][k][f]
    float* pb = part + (((size_t)b * NSPLIT + ns) * K_) * F_;
    #pragma unroll
    for (int i = 0; i < 8; ++i) {
        int k = k0 + i;
        float4 w0 = make_float4(acc[i][0], acc[i][1], acc[i][2], acc[i][3]);
        float4 w1 = make_float4(acc[i][4], acc[i][5], acc[i][6], acc[i][7]);
        *reinterpret_cast<float4*>(pb + (size_t)k * F_ + f0) = w0;
        *reinterpret_cast<float4*>(pb + (size_t)k * F_ + f0 + 128) = w1;
    }
}

// ---------------- Kernel D: reduce partials over NSPLIT ----------------
__global__ __launch_bounds__(256) void reduce_kernel(
    const float* __restrict__ part, float* __restrict__ out)
{
    int idx = (blockIdx.x * 256 + threadIdx.x) * 4;   // over B*K*F = 262144
    int f = idx % F_;
    int bk = idx / F_;          // b*K + k
    int k = bk % K_;
    int b = bk / K_;
    const float* p = part + (((size_t)b * NSPLIT) * K_ + k) * F_ + f;
    float4 s = make_float4(0.f, 0.f, 0.f, 0.f);
    #pragma unroll 4
    for (int ns = 0; ns < NSPLIT; ++ns) {
        float4 v = *reinterpret_cast<const float4*>(p + (size_t)ns * K_ * F_);
        s.x += v.x; s.y += v.y; s.z += v.z; s.w += v.w;
    }
    *reinterpret_cast<float4*>(out + idx) = s;
}

// ---------------- launch ----------------
extern "C" void kernel_launch(void* const* d_in, const int* in_sizes, int n_in,
                              void* d_out, int out_size, void* d_ws, size_t ws_size,
                              hipStream_t stream)
{
    const float* q      = (const float*)d_in[0];
    const float* keys   = (const float*)d_in[1];
    const float* values = (const float*)d_in[2];
    float* out = (float*)d_out;

    char* ws = (char*)d_ws;
    float* sims           = (float*)ws;                                  // B*N*4      = 2 MB
    __hip_bfloat16* omega = (__hip_bfloat16*)(ws + (size_t)B_ * N_ * 4); // B*K*N*2    = 32 MB
    float* part           = (float*)(ws + (size_t)B_ * N_ * 4
                                        + (size_t)B_ * K_ * N_ * 2);     // B*NSPLIT*K*F*4 = 32 MB

    sims_kernel  <<<B_ * (N_ / 1024), 256, 0, stream>>>(q, keys, sims);
    omega_kernel <<<B_, 1024, 0, stream>>>(sims, omega);
    pv_kernel    <<<B_ * NSPLIT, 128, 0, stream>>>(values, omega, part);
    reduce_kernel<<<(B_ * K_ * F_) / 1024, 256, 0, stream>>>(part, out);
}

// Round 2
// 343.483 us; speedup vs baseline: 2.1086x; 2.1086x over previous
//
#include <hip/hip_runtime.h>
#include <hip/hip_bf16.h>

#define B_ 32
#define D_ 256
#define N_ 16384
#define F_ 256
#define K_ 32

#define NSPLIT 32
#define NSLICE (N_ / NSPLIT)   // 512
#define NT 16
#define FPAD 260               // 16B-aligned row stride for v tile (n-major)
#define OPAD 36                // 16B-aligned row stride for omega tile (n-major)

#define L2E 1.4426950408889634f

__device__ __forceinline__ float bf2f(unsigned short u) {
    unsigned int x = ((unsigned int)u) << 16;
    return __uint_as_float(x);
}

// RNE pack of two f32 -> two bf16 in one dword (x in low, y in high)
__device__ __forceinline__ unsigned int pack_bf16(float x, float y) {
    unsigned int ux = __float_as_uint(x), uy = __float_as_uint(y);
    ux = (ux + 0x7FFFu + ((ux >> 16) & 1u)) >> 16;
    uy = (uy + 0x7FFFu + ((uy >> 16) & 1u)) & 0xFFFF0000u;
    return ux | uy;
}

// ---------------- Kernel A: sims[b][n] = -(sum_d q[b][d]*keys[b][d][n]) / 16 ----------------
__global__ __launch_bounds__(256) void sims_kernel(
    const float* __restrict__ q, const float* __restrict__ keys, float* __restrict__ sims)
{
    const int nt = N_ / 1024;                 // 16 n-tiles per batch
    int b = blockIdx.x / nt;
    int tile = blockIdx.x % nt;
    int n0 = tile * 1024 + threadIdx.x * 4;

    __shared__ float qs[D_];
    qs[threadIdx.x] = q[b * D_ + threadIdx.x];   // blockDim == D_ == 256
    __syncthreads();

    const float* kb = keys + (size_t)b * D_ * N_ + n0;
    float ax = 0.f, ay = 0.f, az = 0.f, aw = 0.f;
    #pragma unroll 4
    for (int d = 0; d < D_; ++d) {
        float4 kv = *reinterpret_cast<const float4*>(kb + (size_t)d * N_);
        float qd = qs[d];
        ax = fmaf(qd, kv.x, ax); ay = fmaf(qd, kv.y, ay);
        az = fmaf(qd, kv.z, az); aw = fmaf(qd, kv.w, aw);
    }
    const float sc = -0.0625f;   // -1/sqrt(256)
    float4 o = make_float4(ax * sc, ay * sc, az * sc, aw * sc);
    *reinterpret_cast<float4*>(sims + b * N_ + n0) = o;
}

// ---------------- block reductions (1024 threads = 16 waves) ----------------
__device__ __forceinline__ float blk_max(float v, volatile float* red) {
    #pragma unroll
    for (int off = 32; off > 0; off >>= 1) v = fmaxf(v, __shfl_xor(v, off));
    if ((threadIdx.x & 63) == 0) red[threadIdx.x >> 6] = v;
    __syncthreads();
    if (threadIdx.x < 64) {
        float w = (threadIdx.x < 16) ? red[threadIdx.x] : -3.0e38f;
        #pragma unroll
        for (int off = 8; off > 0; off >>= 1) w = fmaxf(w, __shfl_xor(w, off));
        if (threadIdx.x == 0) red[16] = w;
    }
    __syncthreads();
    return red[16];
}
__device__ __forceinline__ float blk_sum(float v, volatile float* red) {
    #pragma unroll
    for (int off = 32; off > 0; off >>= 1) v += __shfl_xor(v, off);
    if ((threadIdx.x & 63) == 0) red[threadIdx.x >> 6] = v;
    __syncthreads();
    if (threadIdx.x < 64) {
        float w = (threadIdx.x < 16) ? red[threadIdx.x] : 0.0f;
        #pragma unroll
        for (int off = 8; off > 0; off >>= 1) w += __shfl_xor(w, off);
        if (threadIdx.x == 0) red[16] = w;
    }
    __syncthreads();
    return red[16];
}

// ---------------- Kernel B: omega iterations (one 1024-thread block per batch) ----------------
// Maintains q[j] = 2*log2(e)*alpha[n]. Per iteration:
//   e = exp2(q) = exp(2*alpha); Z = block_sum(e); om = e/Z;
//   q += 2*log2(1-om)   [v_log for om>1/16, cubic/quartic poly otherwise]
// No per-iteration max needed: alpha <= 1 always -> exp(2*alpha) <= e^2.
__global__ __launch_bounds__(1024) void omega_kernel(
    const float* __restrict__ sims, __hip_bfloat16* __restrict__ omega)
{
    int b = blockIdx.x, t = threadIdx.x;
    __shared__ float red1[17];
    __shared__ float red2[17];

    // thread t owns 16 contiguous n: [16t, 16t+16)
    const float* sb = sims + (size_t)b * N_ + t * 16;
    float a[16];
    #pragma unroll
    for (int j = 0; j < 16; j += 4) {
        float4 v = *reinterpret_cast<const float4*>(sb + j);
        a[j] = v.x; a[j + 1] = v.y; a[j + 2] = v.z; a[j + 3] = v.w;
    }
    float m0 = -3.0e38f;
    #pragma unroll
    for (int j = 0; j < 16; ++j) m0 = fmaxf(m0, a[j]);
    m0 = blk_max(m0, red1);

    float zs = 0.f;
    #pragma unroll
    for (int j = 0; j < 16; ++j) {
        a[j] = __builtin_amdgcn_exp2f((a[j] - m0) * L2E);
        zs += a[j];
    }
    float Z = blk_sum(zs, red2);
    float c = 2.0f * L2E / Z;      // q = 2*L2E*alpha0
    #pragma unroll
    for (int j = 0; j < 16; ++j) a[j] *= c;

    unsigned int* ob32 = reinterpret_cast<unsigned int*>(omega) + (size_t)b * K_ * (N_ / 2) + t * 8;

    for (int k = 0; k < K_; ++k) {
        float e[16]; float zz = 0.f;
        #pragma unroll
        for (int j = 0; j < 16; ++j) { e[j] = __builtin_amdgcn_exp2f(a[j]); zz += e[j]; }
        float Zk = blk_sum(zz, red2);
        float izk = 1.0f / Zk;
        unsigned int pk[8];
        #pragma unroll
        for (int j = 0; j < 16; ++j) {
            float om = e[j] * izk;
            if ((j & 1) == 0) pk[j >> 1] = pack_bf16(om, 0.f);
            else              pk[j >> 1] |= pack_bf16(0.f, om);
            // lg = log2(1 - om)
            float poly = fmaf(om, fmaf(om, fmaf(om, 0.25f, 0.3333333333f), 0.5f), 1.0f);
            float lg_small = -L2E * om * poly;
            float lg_big = __builtin_amdgcn_logf(1.0f - om);
            float lg = (om > 0.0625f) ? lg_big : lg_small;
            a[j] = fmaf(2.0f, lg, a[j]);
        }
        unsigned int* orow = ob32 + (size_t)k * (N_ / 2);
        *reinterpret_cast<uint4*>(orow)     = make_uint4(pk[0], pk[1], pk[2], pk[3]);
        *reinterpret_cast<uint4*>(orow + 4) = make_uint4(pk[4], pk[5], pk[6], pk[7]);
    }
}

// ---------------- Kernel C: partial PV: part[b][ns][k][f] = sum_{n in slice} om[k][n]*v[f][n] --
__global__ __launch_bounds__(128) void pv_kernel(
    const float* __restrict__ values, const __hip_bfloat16* __restrict__ omega,
    float* __restrict__ part)
{
    int ns = blockIdx.x % NSPLIT;
    int b  = blockIdx.x / NSPLIT;
    int t = threadIdx.x;
    int kg = t >> 5;            // 0..3
    int fg = t & 31;            // 0..31
    int k0 = kg * 8;
    int f0 = fg * 4;

    __shared__ float vs[NT][FPAD];   // n-major v tile
    __shared__ float os[NT][OPAD];   // n-major omega tile

    float acc[8][8];
    #pragma unroll
    for (int i = 0; i < 8; ++i)
        #pragma unroll
        for (int j = 0; j < 8; ++j) acc[i][j] = 0.f;

    const float* vb = values + (size_t)b * F_ * N_;
    const unsigned short* ob = reinterpret_cast<const unsigned short*>(omega) + (size_t)b * K_ * N_;
    int nbase0 = ns * NSLICE;

    int sr = t >> 2;            // 0..31 (row base: f for v, k for omega)
    int sc = (t & 3) * 4;       // 0,4,8,12 (n offset)

    for (int nb = 0; nb < NSLICE; nb += NT) {
        int nbase = nbase0 + nb;
        __syncthreads();   // previous-iter LDS reads done
        // stage v: 256 f x 16 n, transposed into LDS
        #pragma unroll
        for (int p = 0; p < 8; ++p) {
            int f = sr + 32 * p;
            float4 vv = *reinterpret_cast<const float4*>(vb + (size_t)f * N_ + nbase + sc);
            vs[sc + 0][f] = vv.x;
            vs[sc + 1][f] = vv.y;
            vs[sc + 2][f] = vv.z;
            vs[sc + 3][f] = vv.w;
        }
        // stage omega: 32 k x 16 n (bf16 -> f32), transposed
        {
            ushort4 ov = *reinterpret_cast<const ushort4*>(ob + (size_t)sr * N_ + nbase + sc);
            os[sc + 0][sr] = bf2f(ov.x);
            os[sc + 1][sr] = bf2f(ov.y);
            os[sc + 2][sr] = bf2f(ov.z);
            os[sc + 3][sr] = bf2f(ov.w);
        }
        __syncthreads();
        // compute: per n, 4x b128 reads (contiguous-512B across wave) + 64 FMA
        #pragma unroll
        for (int n = 0; n < NT; ++n) {
            float4 o0  = *reinterpret_cast<const float4*>(&os[n][k0]);
            float4 o1  = *reinterpret_cast<const float4*>(&os[n][k0 + 4]);
            float4 va  = *reinterpret_cast<const float4*>(&vs[n][f0]);
            float4 vb4 = *reinterpret_cast<const float4*>(&vs[n][f0 + 128]);
            float om[8] = {o0.x, o0.y, o0.z, o0.w, o1.x, o1.y, o1.z, o1.w};
            float vv[8] = {va.x, va.y, va.z, va.w, vb4.x, vb4.y, vb4.z, vb4.w};
            #pragma unroll
            for (int i = 0; i < 8; ++i)
                #pragma unroll
                for (int j = 0; j < 8; ++j)
                    acc[i][j] = fmaf(om[i], vv[j], acc[i][j]);
        }
    }

    // write partials: part[b][ns][k][f]
    float* pb = part + (((size_t)b * NSPLIT + ns) * K_) * F_;
    #pragma unroll
    for (int i = 0; i < 8; ++i) {
        int k = k0 + i;
        float4 w0 = make_float4(acc[i][0], acc[i][1], acc[i][2], acc[i][3]);
        float4 w1 = make_float4(acc[i][4], acc[i][5], acc[i][6], acc[i][7]);
        *reinterpret_cast<float4*>(pb + (size_t)k * F_ + f0) = w0;
        *reinterpret_cast<float4*>(pb + (size_t)k * F_ + f0 + 128) = w1;
    }
}

// ---------------- Kernel D: reduce partials over NSPLIT ----------------
__global__ __launch_bounds__(256) void reduce_kernel(
    const float* __restrict__ part, float* __restrict__ out)
{
    int idx = (blockIdx.x * 256 + threadIdx.x) * 4;   // over B*K*F = 262144
    int f = idx % F_;
    int bk = idx / F_;          // b*K + k
    int k = bk % K_;
    int b = bk / K_;
    const float* p = part + (((size_t)b * NSPLIT) * K_ + k) * F_ + f;
    float4 s = make_float4(0.f, 0.f, 0.f, 0.f);
    #pragma unroll 4
    for (int ns = 0; ns < NSPLIT; ++ns) {
        float4 v = *reinterpret_cast<const float4*>(p + (size_t)ns * K_ * F_);
        s.x += v.x; s.y += v.y; s.z += v.z; s.w += v.w;
    }
    *reinterpret_cast<float4*>(out + idx) = s;
}

// ---------------- launch ----------------
extern "C" void kernel_launch(void* const* d_in, const int* in_sizes, int n_in,
                              void* d_out, int out_size, void* d_ws, size_t ws_size,
                              hipStream_t stream)
{
    const float* q      = (const float*)d_in[0];
    const float* keys   = (const float*)d_in[1];
    const float* values = (const float*)d_in[2];
    float* out = (float*)d_out;

    char* ws = (char*)d_ws;
    float* sims           = (float*)ws;                                  // B*N*4      = 2 MB
    __hip_bfloat16* omega = (__hip_bfloat16*)(ws + (size_t)B_ * N_ * 4); // B*K*N*2    = 32 MB
    float* part           = (float*)(ws + (size_t)B_ * N_ * 4
                                        + (size_t)B_ * K_ * N_ * 2);     // B*NSPLIT*K*F*4 = 32 MB

    sims_kernel  <<<B_ * (N_ / 1024), 256, 0, stream>>>(q, keys, sims);
    omega_kernel <<<B_, 1024, 0, stream>>>(sims, omega);
    pv_kernel    <<<B_ * NSPLIT, 128, 0, stream>>>(values, omega, part);
    reduce_kernel<<<(B_ * K_ * F_) / 1024, 256, 0, stream>>>(part, out);
}

// Round 3
// 299.047 us; speedup vs baseline: 2.4220x; 1.1486x over previous
//
#include <hip/hip_runtime.h>
#include <hip/hip_bf16.h>

#define B_ 32
#define D_ 256
#define N_ 16384
#define F_ 256
#define K_ 32

#define NSPLIT 16
#define NSLICE (N_ / NSPLIT)   // 1024

#define L2E 1.4426950408889634f

typedef __attribute__((ext_vector_type(8))) short bf16x8;
typedef __attribute__((ext_vector_type(4))) float f32x4;

__device__ __forceinline__ unsigned short f2bf(float x) {
    unsigned int u = __float_as_uint(x);
    u = (u + 0x7FFFu + ((u >> 16) & 1u)) >> 16;
    return (unsigned short)u;
}

// RNE pack of two f32 -> two bf16 in one dword (x in low, y in high)
__device__ __forceinline__ unsigned int pack_bf16(float x, float y) {
    unsigned int ux = __float_as_uint(x), uy = __float_as_uint(y);
    ux = (ux + 0x7FFFu + ((ux >> 16) & 1u)) >> 16;
    uy = (uy + 0x7FFFu + ((uy >> 16) & 1u)) & 0xFFFF0000u;
    return ux | uy;
}

// ---------------- Kernel A: sims[b][n] = -(sum_d q[b][d]*keys[b][d][n]) / 16 ----------------
__global__ __launch_bounds__(256) void sims_kernel(
    const float* __restrict__ q, const float* __restrict__ keys, float* __restrict__ sims)
{
    const int nt = N_ / 1024;                 // 16 n-tiles per batch
    int b = blockIdx.x / nt;
    int tile = blockIdx.x % nt;
    int n0 = tile * 1024 + threadIdx.x * 4;

    __shared__ float qs[D_];
    qs[threadIdx.x] = q[b * D_ + threadIdx.x];   // blockDim == D_ == 256
    __syncthreads();

    const float* kb = keys + (size_t)b * D_ * N_ + n0;
    float ax = 0.f, ay = 0.f, az = 0.f, aw = 0.f;
    #pragma unroll 4
    for (int d = 0; d < D_; ++d) {
        float4 kv = *reinterpret_cast<const float4*>(kb + (size_t)d * N_);
        float qd = qs[d];
        ax = fmaf(qd, kv.x, ax); ay = fmaf(qd, kv.y, ay);
        az = fmaf(qd, kv.z, az); aw = fmaf(qd, kv.w, aw);
    }
    const float sc = -0.0625f;   // -1/sqrt(256)
    float4 o = make_float4(ax * sc, ay * sc, az * sc, aw * sc);
    *reinterpret_cast<float4*>(sims + b * N_ + n0) = o;
}

// ---------------- block reductions (1024 threads = 16 waves) ----------------
__device__ __forceinline__ float blk_max(float v, volatile float* red) {
    #pragma unroll
    for (int off = 32; off > 0; off >>= 1) v = fmaxf(v, __shfl_xor(v, off));
    if ((threadIdx.x & 63) == 0) red[threadIdx.x >> 6] = v;
    __syncthreads();
    if (threadIdx.x < 64) {
        float w = (threadIdx.x < 16) ? red[threadIdx.x] : -3.0e38f;
        #pragma unroll
        for (int off = 8; off > 0; off >>= 1) w = fmaxf(w, __shfl_xor(w, off));
        if (threadIdx.x == 0) red[16] = w;
    }
    __syncthreads();
    return red[16];
}
__device__ __forceinline__ float blk_sum(float v, volatile float* red) {
    #pragma unroll
    for (int off = 32; off > 0; off >>= 1) v += __shfl_xor(v, off);
    if ((threadIdx.x & 63) == 0) red[threadIdx.x >> 6] = v;
    __syncthreads();
    if (threadIdx.x < 64) {
        float w = (threadIdx.x < 16) ? red[threadIdx.x] : 0.0f;
        #pragma unroll
        for (int off = 8; off > 0; off >>= 1) w += __shfl_xor(w, off);
        if (threadIdx.x == 0) red[16] = w;
    }
    __syncthreads();
    return red[16];
}

// ---------------- Kernel B: omega iterations (one 1024-thread block per batch) ----------------
// Tracks w[n] = exp(2*alpha[n]). Per iteration (NO transcendentals):
//   Z = block_sum(w); om = w/Z; store bf16(om); w *= (1-om)^2
// since alpha' = alpha + log1p(-om)  =>  exp(2*alpha') = exp(2*alpha)*(1-om)^2.
__global__ __launch_bounds__(1024) void omega_kernel(
    const float* __restrict__ sims, __hip_bfloat16* __restrict__ omega)
{
    int b = blockIdx.x, t = threadIdx.x;
    __shared__ float red1[17];
    __shared__ float red2[17];

    // thread t owns 16 contiguous n: [16t, 16t+16)
    const float* sb = sims + (size_t)b * N_ + t * 16;
    float a[16];
    #pragma unroll
    for (int j = 0; j < 16; j += 4) {
        float4 v = *reinterpret_cast<const float4*>(sb + j);
        a[j] = v.x; a[j + 1] = v.y; a[j + 2] = v.z; a[j + 3] = v.w;
    }
    float m0 = -3.0e38f;
    #pragma unroll
    for (int j = 0; j < 16; ++j) m0 = fmaxf(m0, a[j]);
    m0 = blk_max(m0, red1);

    float zs = 0.f;
    #pragma unroll
    for (int j = 0; j < 16; ++j) {
        a[j] = __builtin_amdgcn_exp2f((a[j] - m0) * L2E);
        zs += a[j];
    }
    float Z = blk_sum(zs, red2);
    float c2 = 2.0f * L2E / Z;     // alpha0 = a/Z; w = exp2(c2 * a)
    #pragma unroll
    for (int j = 0; j < 16; ++j) a[j] = __builtin_amdgcn_exp2f(a[j] * c2);

    unsigned int* ob32 = reinterpret_cast<unsigned int*>(omega) + (size_t)b * K_ * (N_ / 2) + t * 8;

    for (int k = 0; k < K_; ++k) {
        float zz = 0.f;
        #pragma unroll
        for (int j = 0; j < 16; ++j) zz += a[j];
        float Zk = blk_sum(zz, red2);
        float izk = 1.0f / Zk;
        unsigned int pk[8];
        #pragma unroll
        for (int j = 0; j < 16; j += 2) {
            float om0 = a[j] * izk;
            float om1 = a[j + 1] * izk;
            pk[j >> 1] = pack_bf16(om0, om1);
            float u0 = 1.0f - om0, u1 = 1.0f - om1;
            a[j]     *= u0 * u0;
            a[j + 1] *= u1 * u1;
        }
        unsigned int* orow = ob32 + (size_t)k * (N_ / 2);
        *reinterpret_cast<uint4*>(orow)     = make_uint4(pk[0], pk[1], pk[2], pk[3]);
        *reinterpret_cast<uint4*>(orow + 4) = make_uint4(pk[4], pk[5], pk[6], pk[7]);
    }
}

// ---------------- Kernel C: MFMA PV: part[b][ns][k][f] = sum_{n in slice} om[k][n]*v[f][n] ----
// C = A * B^T pattern: A = omega [K][N] (bf16, contraction-contiguous),
// B^T = values [F][N] (f32 -> bf16 in-register, contraction-contiguous).
// Wave: 64 f x 32 k; WG = 4 waves = 256 f. No LDS.
__global__ __launch_bounds__(256) void pv_kernel(
    const float* __restrict__ values, const __hip_bfloat16* __restrict__ omega,
    float* __restrict__ part)
{
    int ns = blockIdx.x % NSPLIT;
    int b  = blockIdx.x / NSPLIT;
    int t = threadIdx.x;
    int wv = t >> 6;            // wave 0..3
    int l  = t & 63;
    int lr = l & 15;            // row-of-A / row-of-B^T (k / f within tile)
    int lq = l >> 4;            // 0..3 -> contraction sub-offset *8
    int fbase = wv * 64;

    const float* vb = values + (size_t)b * F_ * N_;
    const unsigned short* ob = reinterpret_cast<const unsigned short*>(omega) + (size_t)b * K_ * N_;
    int n0 = ns * NSLICE;

    f32x4 acc[4][2];
    #pragma unroll
    for (int ti = 0; ti < 4; ++ti)
        #pragma unroll
        for (int kt = 0; kt < 2; ++kt)
            acc[ti][kt] = (f32x4){0.f, 0.f, 0.f, 0.f};

    const unsigned short* pa = ob + (size_t)lr * N_ + n0 + lq * 8;

    for (int nb = 0; nb < NSLICE; nb += 32) {
        bf16x8 a0 = *reinterpret_cast<const bf16x8*>(pa + nb);
        bf16x8 a1 = *reinterpret_cast<const bf16x8*>(pa + 16 * N_ + nb);
        #pragma unroll
        for (int ti = 0; ti < 4; ++ti) {
            const float* vp = vb + (size_t)(fbase + ti * 16 + lr) * N_ + n0 + nb + lq * 8;
            float4 x0 = *reinterpret_cast<const float4*>(vp);
            float4 x1 = *reinterpret_cast<const float4*>(vp + 4);
            union { unsigned short s[8]; bf16x8 v; } bv;
            bv.s[0] = f2bf(x0.x); bv.s[1] = f2bf(x0.y);
            bv.s[2] = f2bf(x0.z); bv.s[3] = f2bf(x0.w);
            bv.s[4] = f2bf(x1.x); bv.s[5] = f2bf(x1.y);
            bv.s[6] = f2bf(x1.z); bv.s[7] = f2bf(x1.w);
            acc[ti][0] = __builtin_amdgcn_mfma_f32_16x16x32_bf16(a0, bv.v, acc[ti][0], 0, 0, 0);
            acc[ti][1] = __builtin_amdgcn_mfma_f32_16x16x32_bf16(a1, bv.v, acc[ti][1], 0, 0, 0);
        }
    }

    // write partials: part[b][ns][k][f];  D layout: col(f)=lane&15, row(k)=(lane>>4)*4+reg
    float* pb = part + ((size_t)(b * NSPLIT + ns) * K_) * F_;
    #pragma unroll
    for (int ti = 0; ti < 4; ++ti) {
        int f = fbase + ti * 16 + lr;
        #pragma unroll
        for (int kt = 0; kt < 2; ++kt) {
            #pragma unroll
            for (int r = 0; r < 4; ++r) {
                int k = kt * 16 + lq * 4 + r;
                pb[(size_t)k * F_ + f] = acc[ti][kt][r];
            }
        }
    }
}

// ---------------- Kernel D: reduce partials over NSPLIT ----------------
__global__ __launch_bounds__(256) void reduce_kernel(
    const float* __restrict__ part, float* __restrict__ out)
{
    int idx = (blockIdx.x * 256 + threadIdx.x) * 4;   // over B*K*F = 262144
    int f = idx % F_;
    int bk = idx / F_;          // b*K + k
    int k = bk % K_;
    int b = bk / K_;
    const float* p = part + (((size_t)b * NSPLIT) * K_ + k) * F_ + f;
    float4 s = make_float4(0.f, 0.f, 0.f, 0.f);
    #pragma unroll 4
    for (int ns = 0; ns < NSPLIT; ++ns) {
        float4 v = *reinterpret_cast<const float4*>(p + (size_t)ns * K_ * F_);
        s.x += v.x; s.y += v.y; s.z += v.z; s.w += v.w;
    }
    *reinterpret_cast<float4*>(out + idx) = s;
}

// ---------------- launch ----------------
extern "C" void kernel_launch(void* const* d_in, const int* in_sizes, int n_in,
                              void* d_out, int out_size, void* d_ws, size_t ws_size,
                              hipStream_t stream)
{
    const float* q      = (const float*)d_in[0];
    const float* keys   = (const float*)d_in[1];
    const float* values = (const float*)d_in[2];
    float* out = (float*)d_out;

    char* ws = (char*)d_ws;
    float* sims           = (float*)ws;                                  // B*N*4      = 2 MB
    __hip_bfloat16* omega = (__hip_bfloat16*)(ws + (size_t)B_ * N_ * 4); // B*K*N*2    = 32 MB
    float* part           = (float*)(ws + (size_t)B_ * N_ * 4
                                        + (size_t)B_ * K_ * N_ * 2);     // B*NSPLIT*K*F*4 = 16 MB

    sims_kernel  <<<B_ * (N_ / 1024), 256, 0, stream>>>(q, keys, sims);
    omega_kernel <<<B_, 1024, 0, stream>>>(sims, omega);
    pv_kernel    <<<B_ * NSPLIT, 256, 0, stream>>>(values, omega, part);
    reduce_kernel<<<(B_ * K_ * F_) / 1024, 256, 0, stream>>>(part, out);
}

// Round 4
// 271.536 us; speedup vs baseline: 2.6673x; 1.1013x over previous
//
#include <hip/hip_runtime.h>
#include <hip/hip_bf16.h>

#define B_ 32
#define D_ 256
#define N_ 16384
#define F_ 256
#define K_ 32

#define NSPLIT 16
#define NSLICE (N_ / NSPLIT)   // 1024

#define L2E 1.4426950408889634f

typedef __attribute__((ext_vector_type(8))) short bf16x8;
typedef __attribute__((ext_vector_type(4))) float f32x4;

__device__ __forceinline__ unsigned short f2bf(float x) {
    unsigned int u = __float_as_uint(x);
    u = (u + 0x7FFFu + ((u >> 16) & 1u)) >> 16;
    return (unsigned short)u;
}

// RNE pack of two f32 -> two bf16 in one dword (x in low, y in high)
__device__ __forceinline__ unsigned int pack_bf16(float x, float y) {
    unsigned int ux = __float_as_uint(x), uy = __float_as_uint(y);
    ux = (ux + 0x7FFFu + ((ux >> 16) & 1u)) >> 16;
    uy = (uy + 0x7FFFu + ((uy >> 16) & 1u)) & 0xFFFF0000u;
    return ux | uy;
}

// ---------------- Kernel A: sims[b][n] = -(sum_d q[b][d]*keys[b][d][n]) / 16 ----------------
__global__ __launch_bounds__(256) void sims_kernel(
    const float* __restrict__ q, const float* __restrict__ keys, float* __restrict__ sims)
{
    const int nt = N_ / 1024;                 // 16 n-tiles per batch
    int b = blockIdx.x / nt;
    int tile = blockIdx.x % nt;
    int n0 = tile * 1024 + threadIdx.x * 4;

    __shared__ float qs[D_];
    qs[threadIdx.x] = q[b * D_ + threadIdx.x];   // blockDim == D_ == 256
    __syncthreads();

    const float* kb = keys + (size_t)b * D_ * N_ + n0;
    float ax = 0.f, ay = 0.f, az = 0.f, aw = 0.f;
    #pragma unroll 4
    for (int d = 0; d < D_; ++d) {
        float4 kv = *reinterpret_cast<const float4*>(kb + (size_t)d * N_);
        float qd = qs[d];
        ax = fmaf(qd, kv.x, ax); ay = fmaf(qd, kv.y, ay);
        az = fmaf(qd, kv.z, az); aw = fmaf(qd, kv.w, aw);
    }
    const float sc = -0.0625f;   // -1/sqrt(256)
    float4 o = make_float4(ax * sc, ay * sc, az * sc, aw * sc);
    *reinterpret_cast<float4*>(sims + b * N_ + n0) = o;
}

// ---------------- block reductions (1024 threads = 16 waves) ----------------
__device__ __forceinline__ float blk_max(float v, volatile float* red) {
    #pragma unroll
    for (int off = 32; off > 0; off >>= 1) v = fmaxf(v, __shfl_xor(v, off));
    if ((threadIdx.x & 63) == 0) red[threadIdx.x >> 6] = v;
    __syncthreads();
    if (threadIdx.x < 64) {
        float w = (threadIdx.x < 16) ? red[threadIdx.x] : -3.0e38f;
        #pragma unroll
        for (int off = 8; off > 0; off >>= 1) w = fmaxf(w, __shfl_xor(w, off));
        if (threadIdx.x == 0) red[16] = w;
    }
    __syncthreads();
    return red[16];
}
__device__ __forceinline__ float blk_sum(float v, volatile float* red) {
    #pragma unroll
    for (int off = 32; off > 0; off >>= 1) v += __shfl_xor(v, off);
    if ((threadIdx.x & 63) == 0) red[threadIdx.x >> 6] = v;
    __syncthreads();
    if (threadIdx.x < 64) {
        float w = (threadIdx.x < 16) ? red[threadIdx.x] : 0.0f;
        #pragma unroll
        for (int off = 8; off > 0; off >>= 1) w += __shfl_xor(w, off);
        if (threadIdx.x == 0) red[16] = w;
    }
    __syncthreads();
    return red[16];
}

// ---------------- Kernel B: zeta — w0[b][n] = exp(2*alpha0[n]) and izeta[b][k] = 1/Z_k ------
// Tracks w[n] = exp(2*alpha[n]); Z_k = sum_n w; w *= (1 - w/Z_k)^2. Stores only w0 + 1/Z_k.
__global__ __launch_bounds__(1024) void zeta_kernel(
    const float* __restrict__ sims, float* __restrict__ w0, float* __restrict__ izeta)
{
    int b = blockIdx.x, t = threadIdx.x;
    __shared__ float red1[17];
    __shared__ float red2[17];

    // thread t owns 16 contiguous n: [16t, 16t+16)
    const float* sb = sims + (size_t)b * N_ + t * 16;
    float a[16];
    #pragma unroll
    for (int j = 0; j < 16; j += 4) {
        float4 v = *reinterpret_cast<const float4*>(sb + j);
        a[j] = v.x; a[j + 1] = v.y; a[j + 2] = v.z; a[j + 3] = v.w;
    }
    float m0 = -3.0e38f;
    #pragma unroll
    for (int j = 0; j < 16; ++j) m0 = fmaxf(m0, a[j]);
    m0 = blk_max(m0, red1);

    float zs = 0.f;
    #pragma unroll
    for (int j = 0; j < 16; ++j) {
        a[j] = __builtin_amdgcn_exp2f((a[j] - m0) * L2E);
        zs += a[j];
    }
    float Z = blk_sum(zs, red2);
    float c2 = 2.0f * L2E / Z;     // alpha0 = a/Z; w = exp2(c2 * a)
    #pragma unroll
    for (int j = 0; j < 16; ++j) a[j] = __builtin_amdgcn_exp2f(a[j] * c2);

    // store w0 (f32, coalesced)
    float* wp = w0 + (size_t)b * N_ + t * 16;
    #pragma unroll
    for (int j = 0; j < 16; j += 4)
        *reinterpret_cast<float4*>(wp + j) = make_float4(a[j], a[j+1], a[j+2], a[j+3]);

    for (int k = 0; k < K_; ++k) {
        float zz = 0.f;
        #pragma unroll
        for (int j = 0; j < 16; ++j) zz += a[j];
        float Zk = blk_sum(zz, red2);
        float izk = 1.0f / Zk;
        if (t == 0) izeta[b * K_ + k] = izk;
        #pragma unroll
        for (int j = 0; j < 16; ++j) {
            float u = 1.0f - a[j] * izk;
            a[j] *= u * u;
        }
    }
}

// ---------------- Kernel C: MFMA PV with in-LDS omega regeneration -------------------------
// part[b][ns][k][f] = sum_{n in slice} om[k][n]*v[f][n]
// Phase 1: regenerate omega tile [32][1024] bf16 into LDS from w0 + izeta (XOR-swizzled).
// Phase 2: C = A*B^T via mfma_16x16x32_bf16; A from LDS, B = values f32->bf16 in-register.
__global__ __launch_bounds__(256) void pv_kernel(
    const float* __restrict__ values, const float* __restrict__ w0,
    const float* __restrict__ izeta, float* __restrict__ part)
{
    int ns = blockIdx.x % NSPLIT;
    int b  = blockIdx.x / NSPLIT;
    int t = threadIdx.x;

    __shared__ unsigned char om_lds[K_ * 2048];   // bf16 [32][1024], 64 KB, swizzled

    int n0 = ns * NSLICE;

    // ---- phase 1: omega tile ----
    {
        float4 u4 = *reinterpret_cast<const float4*>(w0 + (size_t)b * N_ + n0 + t * 4);
        float u[4] = {u4.x, u4.y, u4.z, u4.w};
        const float* zb = izeta + b * K_;
        int colbyte = t * 8;                      // 4 bf16 = 8 bytes
        #pragma unroll 8
        for (int k = 0; k < K_; ++k) {
            float izk = zb[k];                    // uniform scalar load
            float om0 = u[0] * izk, om1 = u[1] * izk;
            float om2 = u[2] * izk, om3 = u[3] * izk;
            unsigned int lo = pack_bf16(om0, om1);
            unsigned int hi = pack_bf16(om2, om3);
            int addr = (k * 2048 + colbyte) ^ ((k & 7) << 4);
            *reinterpret_cast<uint2*>(&om_lds[addr]) = make_uint2(lo, hi);
            float a0 = 1.f - om0, a1 = 1.f - om1, a2 = 1.f - om2, a3 = 1.f - om3;
            u[0] *= a0 * a0; u[1] *= a1 * a1; u[2] *= a2 * a2; u[3] *= a3 * a3;
        }
    }
    __syncthreads();

    // ---- phase 2: MFMA ----
    int wv = t >> 6;            // wave 0..3
    int l  = t & 63;
    int lr = l & 15;            // row within 16-tile (k row for A, f row for B)
    int lq = l >> 4;            // 0..3 -> contraction sub-offset *8
    int fbase = wv * 64;

    const float* vb = values + (size_t)b * F_ * N_;

    f32x4 acc[4][2];
    #pragma unroll
    for (int ti = 0; ti < 4; ++ti)
        #pragma unroll
        for (int kt = 0; kt < 2; ++kt)
            acc[ti][kt] = (f32x4){0.f, 0.f, 0.f, 0.f};

    for (int nb = 0; nb < NSLICE; nb += 32) {
        int cb = (nb + lq * 8) * 2;               // byte col in row
        int xr = (lr & 7) << 4;                   // (lr+16)&7 == lr&7
        bf16x8 a0 = *reinterpret_cast<const bf16x8*>(&om_lds[(lr * 2048 + cb) ^ xr]);
        bf16x8 a1 = *reinterpret_cast<const bf16x8*>(&om_lds[((lr + 16) * 2048 + cb) ^ xr]);
        #pragma unroll
        for (int ti = 0; ti < 4; ++ti) {
            const float* vp = vb + (size_t)(fbase + ti * 16 + lr) * N_ + n0 + nb + lq * 8;
            float4 x0 = *reinterpret_cast<const float4*>(vp);
            float4 x1 = *reinterpret_cast<const float4*>(vp + 4);
            union { unsigned short s[8]; bf16x8 v; } bv;
            bv.s[0] = f2bf(x0.x); bv.s[1] = f2bf(x0.y);
            bv.s[2] = f2bf(x0.z); bv.s[3] = f2bf(x0.w);
            bv.s[4] = f2bf(x1.x); bv.s[5] = f2bf(x1.y);
            bv.s[6] = f2bf(x1.z); bv.s[7] = f2bf(x1.w);
            acc[ti][0] = __builtin_amdgcn_mfma_f32_16x16x32_bf16(a0, bv.v, acc[ti][0], 0, 0, 0);
            acc[ti][1] = __builtin_amdgcn_mfma_f32_16x16x32_bf16(a1, bv.v, acc[ti][1], 0, 0, 0);
        }
    }

    // write partials: part[b][ns][k][f];  D layout: col(f)=lane&15, row(k)=(lane>>4)*4+reg
    float* pb = part + ((size_t)(b * NSPLIT + ns) * K_) * F_;
    #pragma unroll
    for (int ti = 0; ti < 4; ++ti) {
        int f = fbase + ti * 16 + lr;
        #pragma unroll
        for (int kt = 0; kt < 2; ++kt) {
            #pragma unroll
            for (int r = 0; r < 4; ++r) {
                int k = kt * 16 + lq * 4 + r;
                pb[(size_t)k * F_ + f] = acc[ti][kt][r];
            }
        }
    }
}

// ---------------- Kernel D: reduce partials over NSPLIT ----------------
__global__ __launch_bounds__(256) void reduce_kernel(
    const float* __restrict__ part, float* __restrict__ out)
{
    int idx = (blockIdx.x * 256 + threadIdx.x) * 4;   // over B*K*F = 262144
    int f = idx % F_;
    int bk = idx / F_;          // b*K + k
    int k = bk % K_;
    int b = bk / K_;
    const float* p = part + (((size_t)b * NSPLIT) * K_ + k) * F_ + f;
    float4 s = make_float4(0.f, 0.f, 0.f, 0.f);
    #pragma unroll 4
    for (int ns = 0; ns < NSPLIT; ++ns) {
        float4 v = *reinterpret_cast<const float4*>(p + (size_t)ns * K_ * F_);
        s.x += v.x; s.y += v.y; s.z += v.z; s.w += v.w;
    }
    *reinterpret_cast<float4*>(out + idx) = s;
}

// ---------------- launch ----------------
extern "C" void kernel_launch(void* const* d_in, const int* in_sizes, int n_in,
                              void* d_out, int out_size, void* d_ws, size_t ws_size,
                              hipStream_t stream)
{
    const float* q      = (const float*)d_in[0];
    const float* keys   = (const float*)d_in[1];
    const float* values = (const float*)d_in[2];
    float* out = (float*)d_out;

    char* ws = (char*)d_ws;
    float* sims  = (float*)ws;                                   // B*N*4           = 2 MB
    float* w0    = (float*)(ws + (size_t)B_ * N_ * 4);           // B*N*4           = 2 MB
    float* izeta = (float*)(ws + (size_t)2 * B_ * N_ * 4);       // B*K*4           = 4 KB
    float* part  = (float*)(ws + (size_t)2 * B_ * N_ * 4 + 4096);// B*NSPLIT*K*F*4  = 16 MB

    sims_kernel  <<<B_ * (N_ / 1024), 256, 0, stream>>>(q, keys, sims);
    zeta_kernel  <<<B_, 1024, 0, stream>>>(sims, w0, izeta);
    pv_kernel    <<<B_ * NSPLIT, 256, 0, stream>>>(values, w0, izeta, part);
    reduce_kernel<<<(B_ * K_ * F_) / 1024, 256, 0, stream>>>(part, out);
}

// Round 5
// 250.903 us; speedup vs baseline: 2.8867x; 1.0822x over previous
//
#include <hip/hip_runtime.h>
#include <hip/hip_bf16.h>

#define B_ 32
#define D_ 256
#define N_ 16384
#define F_ 256
#define K_ 32

#define NSPLIT 32
#define NSLICE (N_ / NSPLIT)   // 512

#define L2E 1.4426950408889634f

typedef __attribute__((ext_vector_type(8))) short bf16x8;
typedef __attribute__((ext_vector_type(4))) float f32x4;

__device__ __forceinline__ unsigned short f2bf(float x) {
    unsigned int u = __float_as_uint(x);
    u = (u + 0x7FFFu + ((u >> 16) & 1u)) >> 16;
    return (unsigned short)u;
}

// RNE pack of two f32 -> two bf16 in one dword (x in low, y in high)
__device__ __forceinline__ unsigned int pack_bf16(float x, float y) {
    unsigned int ux = __float_as_uint(x), uy = __float_as_uint(y);
    ux = (ux + 0x7FFFu + ((ux >> 16) & 1u)) >> 16;
    uy = (uy + 0x7FFFu + ((uy >> 16) & 1u)) & 0xFFFF0000u;
    return ux | uy;
}

// ---------------- Kernel A: sims[b][n] = -(sum_d q[b][d]*keys[b][d][n]) / 16 ----------------
__global__ __launch_bounds__(256) void sims_kernel(
    const float* __restrict__ q, const float* __restrict__ keys, float* __restrict__ sims)
{
    const int nt = N_ / 1024;                 // 16 n-tiles per batch
    int b = blockIdx.x / nt;
    int tile = blockIdx.x % nt;
    int n0 = tile * 1024 + threadIdx.x * 4;

    __shared__ float qs[D_];
    qs[threadIdx.x] = q[b * D_ + threadIdx.x];   // blockDim == D_ == 256
    __syncthreads();

    const float* kb = keys + (size_t)b * D_ * N_ + n0;
    float ax = 0.f, ay = 0.f, az = 0.f, aw = 0.f;
    #pragma unroll 8
    for (int d = 0; d < D_; ++d) {
        float4 kv = *reinterpret_cast<const float4*>(kb + (size_t)d * N_);
        float qd = qs[d];
        ax = fmaf(qd, kv.x, ax); ay = fmaf(qd, kv.y, ay);
        az = fmaf(qd, kv.z, az); aw = fmaf(qd, kv.w, aw);
    }
    const float sc = -0.0625f;   // -1/sqrt(256)
    float4 o = make_float4(ax * sc, ay * sc, az * sc, aw * sc);
    *reinterpret_cast<float4*>(sims + b * N_ + n0) = o;
}

// ---------------- block reductions (prologue only; 1024 threads = 16 waves) ----------------
__device__ __forceinline__ float blk_max(float v, volatile float* red) {
    #pragma unroll
    for (int off = 32; off > 0; off >>= 1) v = fmaxf(v, __shfl_xor(v, off));
    if ((threadIdx.x & 63) == 0) red[threadIdx.x >> 6] = v;
    __syncthreads();
    if (threadIdx.x < 64) {
        float w = (threadIdx.x < 16) ? red[threadIdx.x] : -3.0e38f;
        #pragma unroll
        for (int off = 8; off > 0; off >>= 1) w = fmaxf(w, __shfl_xor(w, off));
        if (threadIdx.x == 0) red[16] = w;
    }
    __syncthreads();
    return red[16];
}
__device__ __forceinline__ float blk_sum(float v, volatile float* red) {
    #pragma unroll
    for (int off = 32; off > 0; off >>= 1) v += __shfl_xor(v, off);
    if ((threadIdx.x & 63) == 0) red[threadIdx.x >> 6] = v;
    __syncthreads();
    if (threadIdx.x < 64) {
        float w = (threadIdx.x < 16) ? red[threadIdx.x] : 0.0f;
        #pragma unroll
        for (int off = 8; off > 0; off >>= 1) w += __shfl_xor(w, off);
        if (threadIdx.x == 0) red[16] = w;
    }
    __syncthreads();
    return red[16];
}

// ---------------- Kernel B: zeta — w0[b][n] = exp(2*alpha0[n]) and izeta[b][k] = 1/Z_k ------
// Tracks w[n] = exp(2*alpha[n]); Z_k = sum_n w; w *= (1 - w/Z_k)^2. Stores only w0 + 1/Z_k.
// K-loop uses a ONE-barrier reduction: wave shfl-sum -> 16 LDS partials -> barrier ->
// every thread sums the 16 partials locally (ping-pong buffers by parity).
__global__ __launch_bounds__(1024) void zeta_kernel(
    const float* __restrict__ sims, float* __restrict__ w0, float* __restrict__ izeta)
{
    int b = blockIdx.x, t = threadIdx.x;
    __shared__ float red1[17];
    __shared__ float redA[16];
    __shared__ float redB[16];

    // thread t owns 16 contiguous n: [16t, 16t+16)
    const float* sb = sims + (size_t)b * N_ + t * 16;
    float a[16];
    #pragma unroll
    for (int j = 0; j < 16; j += 4) {
        float4 v = *reinterpret_cast<const float4*>(sb + j);
        a[j] = v.x; a[j + 1] = v.y; a[j + 2] = v.z; a[j + 3] = v.w;
    }
    float m0 = -3.0e38f;
    #pragma unroll
    for (int j = 0; j < 16; ++j) m0 = fmaxf(m0, a[j]);
    m0 = blk_max(m0, red1);

    float zs = 0.f;
    #pragma unroll
    for (int j = 0; j < 16; ++j) {
        a[j] = __builtin_amdgcn_exp2f((a[j] - m0) * L2E);
        zs += a[j];
    }
    float Z = blk_sum(zs, red1);
    float c2 = 2.0f * L2E / Z;     // alpha0 = a/Z; w = exp2(c2 * a)
    #pragma unroll
    for (int j = 0; j < 16; ++j) a[j] = __builtin_amdgcn_exp2f(a[j] * c2);

    // store w0 (f32, coalesced)
    float* wp = w0 + (size_t)b * N_ + t * 16;
    #pragma unroll
    for (int j = 0; j < 16; j += 4)
        *reinterpret_cast<float4*>(wp + j) = make_float4(a[j], a[j+1], a[j+2], a[j+3]);
    __syncthreads();   // red1 done before redA reuse pattern starts cleanly

    for (int k = 0; k < K_; ++k) {
        float zz = 0.f;
        #pragma unroll
        for (int j = 0; j < 16; ++j) zz += a[j];
        #pragma unroll
        for (int off = 32; off > 0; off >>= 1) zz += __shfl_xor(zz, off);
        float* buf = (k & 1) ? redB : redA;
        if ((t & 63) == 0) buf[t >> 6] = zz;
        __syncthreads();
        float4 p0 = *reinterpret_cast<float4*>(&buf[0]);
        float4 p1 = *reinterpret_cast<float4*>(&buf[4]);
        float4 p2 = *reinterpret_cast<float4*>(&buf[8]);
        float4 p3 = *reinterpret_cast<float4*>(&buf[12]);
        float Zk = ((p0.x + p0.y) + (p0.z + p0.w)) + ((p1.x + p1.y) + (p1.z + p1.w))
                 + ((p2.x + p2.y) + (p2.z + p2.w)) + ((p3.x + p3.y) + (p3.z + p3.w));
        float izk = 1.0f / Zk;
        if (t == 0) izeta[b * K_ + k] = izk;
        #pragma unroll
        for (int j = 0; j < 16; ++j) {
            float u = 1.0f - a[j] * izk;
            a[j] *= u * u;
        }
    }
}

// ---------------- Kernel C: MFMA PV with in-LDS omega regeneration -------------------------
// part[b][ns][k][f] = sum_{n in slice} om[k][n]*v[f][n]
// Phase 1: regenerate omega tile [32][512] bf16 into LDS from w0 + izeta (XOR-swizzled).
// Phase 2: C = A*B^T via mfma_16x16x32_bf16; A from LDS, B = values f32->bf16 in-register.
__global__ __launch_bounds__(256, 4) void pv_kernel(
    const float* __restrict__ values, const float* __restrict__ w0,
    const float* __restrict__ izeta, float* __restrict__ part)
{
    int ns = blockIdx.x % NSPLIT;
    int b  = blockIdx.x / NSPLIT;
    int t = threadIdx.x;

    __shared__ unsigned char om_lds[K_ * NSLICE * 2];   // bf16 [32][512], 32 KB, swizzled

    int n0 = ns * NSLICE;

    // ---- phase 1: omega tile (thread t owns n = n0+2t, n0+2t+1) ----
    {
        float2 u2 = *reinterpret_cast<const float2*>(w0 + (size_t)b * N_ + n0 + t * 2);
        float u0 = u2.x, u1 = u2.y;
        const float* zb = izeta + b * K_;
        int colbyte = t * 4;                      // 2 bf16 = 4 bytes
        #pragma unroll 8
        for (int k = 0; k < K_; ++k) {
            float izk = zb[k];                    // uniform scalar load
            float om0 = u0 * izk, om1 = u1 * izk;
            int addr = (k * 1024 + colbyte) ^ ((k & 7) << 4);
            *reinterpret_cast<unsigned int*>(&om_lds[addr]) = pack_bf16(om0, om1);
            float a0 = 1.f - om0, a1 = 1.f - om1;
            u0 *= a0 * a0; u1 *= a1 * a1;
        }
    }
    __syncthreads();

    // ---- phase 2: MFMA ----
    int wv = t >> 6;            // wave 0..3
    int l  = t & 63;
    int lr = l & 15;            // row within 16-tile (k row for A, f row for B)
    int lq = l >> 4;            // 0..3 -> contraction sub-offset *8
    int fbase = wv * 64;

    const float* vb = values + (size_t)b * F_ * N_;

    f32x4 acc[4][2];
    #pragma unroll
    for (int ti = 0; ti < 4; ++ti)
        #pragma unroll
        for (int kt = 0; kt < 2; ++kt)
            acc[ti][kt] = (f32x4){0.f, 0.f, 0.f, 0.f};

    int xr = (lr & 7) << 4;     // (lr+16)&7 == lr&7

    for (int nb = 0; nb < NSLICE; nb += 32) {
        int cb = (nb + lq * 8) * 2;               // byte col in row
        bf16x8 a0 = *reinterpret_cast<const bf16x8*>(&om_lds[(lr * 1024 + cb) ^ xr]);
        bf16x8 a1 = *reinterpret_cast<const bf16x8*>(&om_lds[((lr + 16) * 1024 + cb) ^ xr]);
        #pragma unroll
        for (int ti = 0; ti < 4; ++ti) {
            const float* vp = vb + (size_t)(fbase + ti * 16 + lr) * N_ + n0 + nb + lq * 8;
            float4 x0 = *reinterpret_cast<const float4*>(vp);
            float4 x1 = *reinterpret_cast<const float4*>(vp + 4);
            union { unsigned short s[8]; bf16x8 v; } bv;
            bv.s[0] = f2bf(x0.x); bv.s[1] = f2bf(x0.y);
            bv.s[2] = f2bf(x0.z); bv.s[3] = f2bf(x0.w);
            bv.s[4] = f2bf(x1.x); bv.s[5] = f2bf(x1.y);
            bv.s[6] = f2bf(x1.z); bv.s[7] = f2bf(x1.w);
            acc[ti][0] = __builtin_amdgcn_mfma_f32_16x16x32_bf16(a0, bv.v, acc[ti][0], 0, 0, 0);
            acc[ti][1] = __builtin_amdgcn_mfma_f32_16x16x32_bf16(a1, bv.v, acc[ti][1], 0, 0, 0);
        }
    }

    // write partials: part[b][ns][k][f];  D layout: col(f)=lane&15, row(k)=(lane>>4)*4+reg
    float* pb = part + ((size_t)(b * NSPLIT + ns) * K_) * F_;
    #pragma unroll
    for (int ti = 0; ti < 4; ++ti) {
        int f = fbase + ti * 16 + lr;
        #pragma unroll
        for (int kt = 0; kt < 2; ++kt) {
            #pragma unroll
            for (int r = 0; r < 4; ++r) {
                int k = kt * 16 + lq * 4 + r;
                pb[(size_t)k * F_ + f] = acc[ti][kt][r];
            }
        }
    }
}

// ---------------- Kernel D: reduce partials over NSPLIT ----------------
__global__ __launch_bounds__(256) void reduce_kernel(
    const float* __restrict__ part, float* __restrict__ out)
{
    int idx = (blockIdx.x * 256 + threadIdx.x) * 4;   // over B*K*F = 262144
    int f = idx % F_;
    int bk = idx / F_;          // b*K + k
    int k = bk % K_;
    int b = bk / K_;
    const float* p = part + (((size_t)b * NSPLIT) * K_ + k) * F_ + f;
    float4 s = make_float4(0.f, 0.f, 0.f, 0.f);
    #pragma unroll 4
    for (int ns = 0; ns < NSPLIT; ++ns) {
        float4 v = *reinterpret_cast<const float4*>(p + (size_t)ns * K_ * F_);
        s.x += v.x; s.y += v.y; s.z += v.z; s.w += v.w;
    }
    *reinterpret_cast<float4*>(out + idx) = s;
}

// ---------------- launch ----------------
extern "C" void kernel_launch(void* const* d_in, const int* in_sizes, int n_in,
                              void* d_out, int out_size, void* d_ws, size_t ws_size,
                              hipStream_t stream)
{
    const float* q      = (const float*)d_in[0];
    const float* keys   = (const float*)d_in[1];
    const float* values = (const float*)d_in[2];
    float* out = (float*)d_out;

    char* ws = (char*)d_ws;
    float* sims  = (float*)ws;                                   // B*N*4           = 2 MB
    float* w0    = (float*)(ws + (size_t)B_ * N_ * 4);           // B*N*4           = 2 MB
    float* izeta = (float*)(ws + (size_t)2 * B_ * N_ * 4);       // B*K*4           = 4 KB
    float* part  = (float*)(ws + (size_t)2 * B_ * N_ * 4 + 4096);// B*NSPLIT*K*F*4  = 32 MB

    sims_kernel  <<<B_ * (N_ / 1024), 256, 0, stream>>>(q, keys, sims);
    zeta_kernel  <<<B_, 1024, 0, stream>>>(sims, w0, izeta);
    pv_kernel    <<<B_ * NSPLIT, 256, 0, stream>>>(values, w0, izeta, part);
    reduce_kernel<<<(B_ * K_ * F_) / 1024, 256, 0, stream>>>(part, out);
}